// Round 10
// baseline (155.920 us; speedup 1.0000x reference)
//
#include <hip/hip_runtime.h>

typedef unsigned int uint;
typedef _Float16 f16;

typedef __attribute__((ext_vector_type(8))) _Float16 f16x8;
typedef __attribute__((ext_vector_type(2))) _Float16 f16x2;
typedef __attribute__((ext_vector_type(4))) float f32x4;

#define E_CNT 496

// W2 f16 image: [96][264] f16 = 50688 B (stride 264 f16 = 132 dwords).
#define W2_STRIDE 264
#define W2_STAGE_BYTES 52224             // 51 x 1024
#define W2_CHUNKS 51
#define LDS_BYTES 52224

// payoff per-octet overlay region: [2 sides][8 pp][136 f16] = 2176 f16 = 4352 B
#define PP_STRIDE 136
#define V_OFF 1088
#define PW_F16 2176

// x_kernel LDS: hidden [64][132] f32 (33792 B) + X slab [64][264] f16 (33792 B)
#define XS_STRIDE 264
#define XH_BYTES 33792

__device__ __forceinline__ uint pack2_f16(float lo, float hi) {
    union { f16x2 h; uint u; } r;
    r.h[0] = (_Float16)lo;
    r.h[1] = (_Float16)hi;
    return r.u;
}

__device__ __forceinline__ void load_lds16(const void* g, void* l) {
    __builtin_amdgcn_global_load_lds(
        (const __attribute__((address_space(1))) void*)g,
        (__attribute__((address_space(3))) void*)l, 16, 0, 0);
}

// ---------------- X staging via swapped-operand MFMA (R8 structure) --------
// grid = 257; blocks 0..255 = 128 rowblocks x 2 halves; block 256 converts W2.
__global__ __launch_bounds__(256) void x_kernel(
    const float* __restrict__ hidden, const float* __restrict__ W1,
    const float* __restrict__ b1, f16* __restrict__ Xout,
    const float* __restrict__ W2, f16* __restrict__ w2h) {
    __shared__ __align__(16) unsigned char xsmem[XH_BYTES + 64 * XS_STRIDE * 2];
    float* hs = (float*)xsmem;                    // hidden [64][132] f32
    f16* xs = (f16*)(xsmem + XH_BYTES);           // X slab [64][264] f16

    const int tid = threadIdx.x;

    if (blockIdx.x == 256) {
        // convert W2 f32 [96][256] -> f16 image [96][264] (pad never read)
        #pragma unroll
        for (int j = 0; j < 24; ++j) {
            int idx4 = tid + j * 256;
            int n = idx4 >> 6;
            int k = (idx4 & 63) << 2;
            float4 v = *(const float4*)&W2[n * 256 + k];
            uint2 o;
            o.x = pack2_f16(v.x, v.y);
            o.y = pack2_f16(v.z, v.w);
            *(uint2*)&w2h[n * W2_STRIDE + k] = o;
        }
        return;
    }

    const int rowblock = blockIdx.x >> 1;
    const int half = blockIdx.x & 1;
    const int ln = tid & 63;
    const int waveId = tid >> 6;
    const int quad = ln >> 4;
    const int l16 = ln & 15;
    const int row0 = rowblock * 64;

    // stage 64 hidden rows (coalesced float4)
    {
        const float* src = hidden + row0 * 128;
        #pragma unroll
        for (int it = 0; it < 8; ++it) {
            int idx = it * 256 + tid;
            int r = idx >> 5;
            int c4 = idx & 31;
            float4 v = *(const float4*)(src + idx * 4);
            *(float4*)&hs[r * 132 + c4 * 4] = v;
        }
    }
    __syncthreads();

    union FU { uint u[4]; f16x8 v; };

    #pragma unroll
    for (int p = 0; p < 2; ++p) {
        // W1 frags for this pass's 2 n-tiles
        FU wf[2][4];
        float bh[2][4];
        #pragma unroll
        for (int nt = 0; nt < 2; ++nt) {
            const int tl = p * 8 + waveId * 2 + nt;   // htile 0..15 within half
            const float* wrow = W1 + (tl * 16 + l16) * 256 + half * 128 + quad * 8;
            #pragma unroll
            for (int kk = 0; kk < 4; ++kk) {
                float4 v0 = *(const float4*)(wrow + kk * 32);
                float4 v1 = *(const float4*)(wrow + kk * 32 + 4);
                wf[nt][kk].u[0] = pack2_f16(v0.x, v0.y);
                wf[nt][kk].u[1] = pack2_f16(v0.z, v0.w);
                wf[nt][kk].u[2] = pack2_f16(v1.x, v1.y);
                wf[nt][kk].u[3] = pack2_f16(v1.z, v1.w);
            }
            #pragma unroll
            for (int r = 0; r < 4; ++r)
                bh[nt][r] = 0.5f * b1[tl * 16 + quad * 4 + r];
        }

        #pragma unroll
        for (int ch = 0; ch < 4; ++ch) {
            FU hf[4];
            const float* hrow = &hs[(ch * 16 + l16) * 132 + quad * 8];
            #pragma unroll
            for (int kk = 0; kk < 4; ++kk) {
                float4 v0 = *(const float4*)(hrow + kk * 32);
                float4 v1 = *(const float4*)(hrow + kk * 32 + 4);
                hf[kk].u[0] = pack2_f16(v0.x, v0.y);
                hf[kk].u[1] = pack2_f16(v0.z, v0.w);
                hf[kk].u[2] = pack2_f16(v1.x, v1.y);
                hf[kk].u[3] = pack2_f16(v1.z, v1.w);
            }
            #pragma unroll
            for (int nt = 0; nt < 2; ++nt) {
                const int tl = p * 8 + waveId * 2 + nt;
                f32x4 acc = (f32x4){0.f, 0.f, 0.f, 0.f};
                #pragma unroll
                for (int kk = 0; kk < 4; ++kk)
                    acc = __builtin_amdgcn_mfma_f32_16x16x32_f16(wf[nt][kk].v, hf[kk].v, acc, 0, 0, 0);
                uint2 o;
                o.x = pack2_f16(acc[0] + bh[nt][0], acc[1] + bh[nt][1]);
                o.y = pack2_f16(acc[2] + bh[nt][2], acc[3] + bh[nt][3]);
                *(uint2*)&xs[(ch * 16 + l16) * XS_STRIDE + tl * 16 + quad * 4] = o;
            }
        }
    }

    __syncthreads();

    // coalesced readout: 2048 x 16B; 512 B contiguous per row
    f16* xdst = Xout + half * (8192 * 256) + row0 * 256;
    #pragma unroll
    for (int it = 0; it < 8; ++it) {
        int idx = it * 256 + tid;       // 0..2047
        int row = idx >> 5;
        int c8 = idx & 31;
        uint4 v = *(const uint4*)&xs[row * XS_STRIDE + c8 * 8];
        *(uint4*)&xdst[row * 256 + c8 * 8] = v;
    }
}

// ---------------- fused GEMM2 (MFMA, fp16) + MFMA payoff -------------------
// block = 512 thr = 8 waves; SPLIT-TT WAVE PAIRING: waves (2w,2w+1) co-own
// 16 pairs; even wave computes tt 0-2 (n 0-47), odd tt 3-5 (n 48-95), each
// for both 8-pair octets -> per-wave W2 ds_read halves (48 -> 24). MFMA
// count unchanged. 64 pairs/block; grid 1984 XCD-swizzled. W2 staged ONCE;
// depth-2 X prefetch per octet; 3 barriers total.
__global__ __launch_bounds__(512, 6) void gemm_payoff_kernel(
    const f16* __restrict__ X1, const f16* __restrict__ X2,
    const int* __restrict__ e_f, const int* __restrict__ e_t,
    const f16* __restrict__ w2g, const float* __restrict__ b2,
    float* __restrict__ out) {

    __shared__ __align__(16) unsigned char smem[LDS_BYTES];
    f16* w2s = (f16*)smem;

    const int tid = threadIdx.x;
    const int ln = tid & 63;
    const int waveId = tid >> 6;
    const int quad = ln >> 4;
    const int l16 = ln & 15;
    const int pl = l16 & 7;
    const int s = l16 >> 3;
    const int ttBase = (waveId & 1) * 3;      // tt half owned by this wave

    // XCD swizzle: 1984 = 8 * 248 (bijective)
    const int bx = blockIdx.x;
    const int lb = (bx & 7) * 248 + (bx >> 3);

    // stage full W2 image once: 51 x 1KB async chunks, wave-strided
    {
        const unsigned char* src = (const unsigned char*)w2g + ln * 16;
        #pragma unroll
        for (int j = 0; j < 7; ++j) {
            int i = waveId + j * 8;
            if (i < W2_CHUNKS)
                load_lds16(src + i * 1024, smem + i * 1024);
        }
    }

    // edge dtype detect (uniform -> scalar loads)
    bool f64 = true, t64 = true;
    #pragma unroll
    for (int i = 0; i < 16; ++i) {
        if (e_f[2 * i + 1] != 0) f64 = false;
        if (e_t[2 * i + 1] != 0) t64 = false;
    }

    // K-loop pairs: two octets g=0,1 of the wave-pair's 16 pairs
    const int pairGrp = lb * 64 + (waveId & 6) * 8;   // group of 16
    const f16* px1[2];
    const f16* px2[2];
    #pragma unroll
    for (int g = 0; g < 2; ++g) {
        int pair = pairGrp + g * 8 + pl;
        int b = pair / E_CNT;
        int e = pair - b * E_CNT;
        int f = f64 ? e_f[2 * e] : e_f[e];
        int t = t64 ? e_t[2 * e] : e_t[e];
        int n1 = s ? t : f;
        int n2 = s ? f : t;
        px1[g] = X1 + ((b * 32 + n1) * 256 + quad * 8);
        px2[g] = X2 + ((b * 32 + n2) * 256 + quad * 8);
    }

    f32x4 acc[2][3];
    #pragma unroll
    for (int g = 0; g < 2; ++g)
        #pragma unroll
        for (int t3 = 0; t3 < 3; ++t3) acc[g][t3] = (f32x4){0.f, 0.f, 0.f, 0.f};

    typedef union { uint4 q; f16x8 h; } XU;
    XU G1[2][2], G2[2][2];   // [buf][g]
    #pragma unroll
    for (int g = 0; g < 2; ++g) {
        G1[0][g].q = *(const uint4*)(px1[g] + 0 * 32);
        G2[0][g].q = *(const uint4*)(px2[g] + 0 * 32);
        G1[1][g].q = *(const uint4*)(px1[g] + 1 * 32);
        G2[1][g].q = *(const uint4*)(px2[g] + 1 * 32);
    }

    const f16x8 zero8 = (f16x8){0, 0, 0, 0, 0, 0, 0, 0};

    __syncthreads();   // W2 fully staged

    // all 8 kk, no internal barriers; each W2 frag read feeds both octets
    #pragma unroll
    for (int kk = 0; kk < 8; ++kk) {
        const int buf = kk & 1;
        f16x8 af[2];
        #pragma unroll
        for (int g = 0; g < 2; ++g) {
            f16x8 sum = G1[buf][g].h + G2[buf][g].h;
            af[g] = __builtin_elementwise_max(sum, zero8);
        }
        if (kk < 6) {
            #pragma unroll
            for (int g = 0; g < 2; ++g) {
                G1[buf][g].q = *(const uint4*)(px1[g] + (kk + 2) * 32);
                G2[buf][g].q = *(const uint4*)(px2[g] + (kk + 2) * 32);
            }
        }
        #pragma unroll
        for (int t3 = 0; t3 < 3; ++t3) {
            f16x8 bf = *(const f16x8*)&w2s[((ttBase + t3) * 16 + l16) * W2_STRIDE + kk * 32 + quad * 8];
            acc[0][t3] = __builtin_amdgcn_mfma_f32_16x16x32_f16(af[0], bf, acc[0][t3], 0, 0, 0);
            acc[1][t3] = __builtin_amdgcn_mfma_f32_16x16x32_f16(af[1], bf, acc[1][t3], 0, 0, 0);
        }
    }

    // epilogue precompute AFTER the K-loop
    float b2v[3];
    int d6[3];
    float psc[3];
    {
        const int s_ = quad >> 1;
        #pragma unroll
        for (int t3 = 0; t3 < 3; ++t3) {
            int n = (ttBase + t3) * 16 + l16;
            b2v[t3] = b2[n];
            int rr = n / 24;
            int rem = n - rr * 24;
            int c01 = (rem >= 12) ? 1 : 0;
            int a = rem - c01 * 12;
            int k8 = s_ * 4 + rr;
            int toL = (c01 == s_) ? 1 : 0;
            d6[t3] = (toL ? 0 : V_OFF) + (quad & 1) * 4 * PP_STRIDE + a * 8 + k8;
            psc[t3] = toL ? 0.5f : 1.0f;   // fold the 0.5 into the U (left) side
        }
    }

    __syncthreads();   // all waves done reading W2; overlay per-octet regions

    // dump p (+b2, x psc) for BOTH octets into region (waveId&6)+g
    #pragma unroll
    for (int g = 0; g < 2; ++g) {
        f16* pmg = (f16*)smem + ((waveId & 6) + g) * PW_F16;
        #pragma unroll
        for (int t3 = 0; t3 < 3; ++t3) {
            #pragma unroll
            for (int r = 0; r < 4; ++r)
                pmg[d6[t3] + r * PP_STRIDE] = (_Float16)((acc[g][t3][r] + b2v[t3]) * psc[t3]);
        }
    }

    __syncthreads();   // cross-wave: partner's tt-half visible

    // payoff: wave's own octet = region waveId ((waveId&6)+(waveId&1));
    // pairs = lb*64 + waveId*8 + pp. One MFMA per pair, A=V, B=U ->
    // D[col=l16=i][row=quad*4+r=j] -> coalesced float4 stores
    f16* pm = (f16*)smem + waveId * PW_F16;
    const int pairBase = lb * 64 + waveId * 8;
    #pragma unroll
    for (int pp = 0; pp < 8; ++pp) {
        f16x8 afp = zero8, bfp = zero8;
        if (quad == 0) {
            afp = *(const f16x8*)&pm[V_OFF + pp * PP_STRIDE + l16 * 8];
            bfp = *(const f16x8*)&pm[pp * PP_STRIDE + l16 * 8];
        }
        f32x4 d = __builtin_amdgcn_mfma_f32_16x16x32_f16(
            afp, bfp, (f32x4){0.f, 0.f, 0.f, 0.f}, 0, 0, 0);
        if (l16 < 12 && quad < 3) {
            float* ob = out + (pairBase + pp) * 144 + l16 * 12 + quad * 4;
            *(float4*)ob = make_float4(d[0], d[1], d[2], d[3]);
        }
    }
}

extern "C" void kernel_launch(void* const* d_in, const int* in_sizes, int n_in,
                              void* d_out, int out_size, void* d_ws, size_t ws_size,
                              hipStream_t stream) {
    const float* hidden = (const float*)d_in[0];
    const float* W1 = (const float*)d_in[1];
    const float* b1 = (const float*)d_in[2];
    const float* W2 = (const float*)d_in[3];
    const float* b2 = (const float*)d_in[4];
    const int* e_f = (const int*)d_in[5];
    const int* e_t = (const int*)d_in[6];
    float* out = (float*)d_out;

    char* ws = (char*)d_ws;
    f16* X = (f16*)ws;                              // X1 then X2, 4 MB each
    f16* w2h = (f16*)(ws + 8 * 1024 * 1024);        // W2 f16 image [96][264] + stage slop

    x_kernel<<<257, 256, 0, stream>>>(hidden, W1, b1, X, W2, w2h);
    gemm_payoff_kernel<<<1984, 512, 0, stream>>>(X, X + 8192 * 256, e_f, e_t, w2h, b2, out);
}

// Round 12
// 130.834 us; speedup vs baseline: 1.1917x; 1.1917x over previous
//
#include <hip/hip_runtime.h>

typedef unsigned int uint;
typedef _Float16 f16;

typedef __attribute__((ext_vector_type(8))) _Float16 f16x8;
typedef __attribute__((ext_vector_type(2))) _Float16 f16x2;
typedef __attribute__((ext_vector_type(4))) float f32x4;

#define E_CNT 496

// W2 f16 image: [96][264] f16 = 50688 B (stride 264 f16 = 132 dwords).
#define W2_STRIDE 264
#define W2_CHUNKS 51                     // 51 x 1KB staged
#define W2_LDS 52224

// payoff per-wave region (separate from W2 -> no overlay barrier):
// [2 sides][8 pp][136 f16] = 2176 f16 = 4352 B; 8 waves
#define PP_STRIDE 136
#define V_OFF 1088
#define PW_F16 2176
#define GEMM_LDS (W2_LDS + 8 * 4352)     // 87040 B -> 1 block/CU

// x_kernel LDS: hidden [64][132] f32 (33792 B) + X slab [64][264] f16 (33792 B)
#define XS_STRIDE 264
#define XH_BYTES 33792

__device__ __forceinline__ uint pack2_f16(float lo, float hi) {
    union { f16x2 h; uint u; } r;
    r.h[0] = (_Float16)lo;
    r.h[1] = (_Float16)hi;
    return r.u;
}

__device__ __forceinline__ void load_lds16(const void* g, void* l) {
    __builtin_amdgcn_global_load_lds(
        (const __attribute__((address_space(1))) void*)g,
        (__attribute__((address_space(3))) void*)l, 16, 0, 0);
}

// ---------------- X staging via swapped-operand MFMA (R8 structure) --------
// grid = 257; blocks 0..255 = 128 rowblocks x 2 halves; block 256 converts W2.
__global__ __launch_bounds__(256) void x_kernel(
    const float* __restrict__ hidden, const float* __restrict__ W1,
    const float* __restrict__ b1, f16* __restrict__ Xout,
    const float* __restrict__ W2, f16* __restrict__ w2h) {
    __shared__ __align__(16) unsigned char xsmem[XH_BYTES + 64 * XS_STRIDE * 2];
    float* hs = (float*)xsmem;                    // hidden [64][132] f32
    f16* xs = (f16*)(xsmem + XH_BYTES);           // X slab [64][264] f16

    const int tid = threadIdx.x;

    if (blockIdx.x == 256) {
        // convert W2 f32 [96][256] -> f16 image [96][264] (pad never read)
        #pragma unroll
        for (int j = 0; j < 24; ++j) {
            int idx4 = tid + j * 256;
            int n = idx4 >> 6;
            int k = (idx4 & 63) << 2;
            float4 v = *(const float4*)&W2[n * 256 + k];
            uint2 o;
            o.x = pack2_f16(v.x, v.y);
            o.y = pack2_f16(v.z, v.w);
            *(uint2*)&w2h[n * W2_STRIDE + k] = o;
        }
        return;
    }

    const int rowblock = blockIdx.x >> 1;
    const int half = blockIdx.x & 1;
    const int ln = tid & 63;
    const int waveId = tid >> 6;
    const int quad = ln >> 4;
    const int l16 = ln & 15;
    const int row0 = rowblock * 64;

    // stage 64 hidden rows (coalesced float4)
    {
        const float* src = hidden + row0 * 128;
        #pragma unroll
        for (int it = 0; it < 8; ++it) {
            int idx = it * 256 + tid;
            int r = idx >> 5;
            int c4 = idx & 31;
            float4 v = *(const float4*)(src + idx * 4);
            *(float4*)&hs[r * 132 + c4 * 4] = v;
        }
    }
    __syncthreads();

    union FU { uint u[4]; f16x8 v; };

    #pragma unroll
    for (int p = 0; p < 2; ++p) {
        // W1 frags for this pass's 2 n-tiles
        FU wf[2][4];
        float bh[2][4];
        #pragma unroll
        for (int nt = 0; nt < 2; ++nt) {
            const int tl = p * 8 + waveId * 2 + nt;   // htile 0..15 within half
            const float* wrow = W1 + (tl * 16 + l16) * 256 + half * 128 + quad * 8;
            #pragma unroll
            for (int kk = 0; kk < 4; ++kk) {
                float4 v0 = *(const float4*)(wrow + kk * 32);
                float4 v1 = *(const float4*)(wrow + kk * 32 + 4);
                wf[nt][kk].u[0] = pack2_f16(v0.x, v0.y);
                wf[nt][kk].u[1] = pack2_f16(v0.z, v0.w);
                wf[nt][kk].u[2] = pack2_f16(v1.x, v1.y);
                wf[nt][kk].u[3] = pack2_f16(v1.z, v1.w);
            }
            #pragma unroll
            for (int r = 0; r < 4; ++r)
                bh[nt][r] = 0.5f * b1[tl * 16 + quad * 4 + r];
        }

        #pragma unroll
        for (int ch = 0; ch < 4; ++ch) {
            FU hf[4];
            const float* hrow = &hs[(ch * 16 + l16) * 132 + quad * 8];
            #pragma unroll
            for (int kk = 0; kk < 4; ++kk) {
                float4 v0 = *(const float4*)(hrow + kk * 32);
                float4 v1 = *(const float4*)(hrow + kk * 32 + 4);
                hf[kk].u[0] = pack2_f16(v0.x, v0.y);
                hf[kk].u[1] = pack2_f16(v0.z, v0.w);
                hf[kk].u[2] = pack2_f16(v1.x, v1.y);
                hf[kk].u[3] = pack2_f16(v1.z, v1.w);
            }
            #pragma unroll
            for (int nt = 0; nt < 2; ++nt) {
                const int tl = p * 8 + waveId * 2 + nt;
                f32x4 acc = (f32x4){0.f, 0.f, 0.f, 0.f};
                #pragma unroll
                for (int kk = 0; kk < 4; ++kk)
                    acc = __builtin_amdgcn_mfma_f32_16x16x32_f16(wf[nt][kk].v, hf[kk].v, acc, 0, 0, 0);
                uint2 o;
                o.x = pack2_f16(acc[0] + bh[nt][0], acc[1] + bh[nt][1]);
                o.y = pack2_f16(acc[2] + bh[nt][2], acc[3] + bh[nt][3]);
                *(uint2*)&xs[(ch * 16 + l16) * XS_STRIDE + tl * 16 + quad * 4] = o;
            }
        }
    }

    __syncthreads();

    // coalesced readout: 2048 x 16B; 512 B contiguous per row
    f16* xdst = Xout + half * (8192 * 256) + row0 * 256;
    #pragma unroll
    for (int it = 0; it < 8; ++it) {
        int idx = it * 256 + tid;       // 0..2047
        int row = idx >> 5;
        int c8 = idx & 31;
        uint4 v = *(const uint4*)&xs[row * XS_STRIDE + c8 * 8];
        *(uint4*)&xdst[row * 256 + c8 * 8] = v;
    }
}

// ---------------- fused GEMM2 (MFMA, fp16) + MFMA payoff -------------------
// block = 512 thr = 8 waves; grid 248 (single cohort, 8*31 XCD-swizzled).
// Each block processes 8 pair-groups (512 pairs) serially; W2 staged ONCE
// per block; payoff scratch in its OWN LDS region -> exactly ONE barrier in
// the whole kernel; after it, waves run fully decoupled. Next group's X
// chunks issued right after the K-loop so latency hides under dump+payoff.
__global__ __launch_bounds__(512, 2) void gemm_payoff_kernel(
    const f16* __restrict__ X1, const f16* __restrict__ X2,
    const int* __restrict__ e_f, const int* __restrict__ e_t,
    const f16* __restrict__ w2g, const float* __restrict__ b2,
    float* __restrict__ out) {

    __shared__ __align__(16) unsigned char smem[GEMM_LDS];
    f16* w2s = (f16*)smem;
    f16* pmBase = (f16*)(smem + W2_LDS);

    const int tid = threadIdx.x;
    const int ln = tid & 63;
    const int waveId = tid >> 6;
    const int quad = ln >> 4;
    const int l16 = ln & 15;
    const int pl = l16 & 7;
    const int s = l16 >> 3;

    // XCD swizzle: 248 = 8 * 31 (bijective)
    const int bx = blockIdx.x;
    const int lb = (bx & 7) * 31 + (bx >> 3);

    // stage full W2 image once: 51 x 1KB async chunks, wave-strided
    {
        const unsigned char* src = (const unsigned char*)w2g + ln * 16;
        #pragma unroll
        for (int j = 0; j < 7; ++j) {
            int i = waveId + j * 8;
            if (i < W2_CHUNKS)
                load_lds16(src + i * 1024, smem + i * 1024);
        }
    }

    // edge dtype detect (uniform -> scalar loads)
    bool f64 = true, t64 = true;
    #pragma unroll
    for (int i = 0; i < 16; ++i) {
        if (e_f[2 * i + 1] != 0) f64 = false;
        if (e_t[2 * i + 1] != 0) t64 = false;
    }

    // epilogue precompute (group-invariant)
    float b2v[6];
    int d6[6];
    float psc[6];
    {
        const int s_ = quad >> 1;
        #pragma unroll
        for (int tt = 0; tt < 6; ++tt) {
            int n = tt * 16 + l16;
            b2v[tt] = b2[n];
            int rr = n / 24;
            int rem = n - rr * 24;
            int c01 = (rem >= 12) ? 1 : 0;
            int a = rem - c01 * 12;
            int k8 = s_ * 4 + rr;
            int toL = (c01 == s_) ? 1 : 0;
            d6[tt] = (toL ? 0 : V_OFF) + (quad & 1) * 4 * PP_STRIDE + a * 8 + k8;
            psc[tt] = toL ? 0.5f : 1.0f;   // fold the 0.5 into the U (left) side
        }
    }

    auto computePx = [&](int g, const f16*& p1, const f16*& p2) {
        int pair = lb * 512 + g * 64 + waveId * 8 + pl;
        int b = pair / E_CNT;
        int e = pair - b * E_CNT;
        int f = f64 ? e_f[2 * e] : e_f[e];
        int t = t64 ? e_t[2 * e] : e_t[e];
        int n1 = s ? t : f;
        int n2 = s ? f : t;
        p1 = X1 + ((b * 32 + n1) * 256 + quad * 8);
        p2 = X2 + ((b * 32 + n2) * 256 + quad * 8);
    };

    typedef union { uint4 q; f16x8 h; } XU;
    XU G1[4], G2[4];
    const f16* px1;
    const f16* px2;

    computePx(0, px1, px2);
    #pragma unroll
    for (int c = 0; c < 4; ++c) {
        G1[c].q = *(const uint4*)(px1 + c * 32);
        G2[c].q = *(const uint4*)(px2 + c * 32);
    }

    const f16x8 zero8 = (f16x8){0, 0, 0, 0, 0, 0, 0, 0};
    f16* pm = pmBase + waveId * PW_F16;

    __syncthreads();   // THE barrier: W2 staged. No syncs after this point.

    f32x4 acc[6];

    #pragma unroll 1
    for (int g = 0; g < 8; ++g) {
        #pragma unroll
        for (int tt = 0; tt < 6; ++tt) acc[tt] = (f32x4){0.f, 0.f, 0.f, 0.f};

        // K-loop: depth-4 circular X prefetch within the group
        #pragma unroll
        for (int kk = 0; kk < 8; ++kk) {
            const int buf = kk & 3;
            f16x8 sum = G1[buf].h + G2[buf].h;
            f16x8 af = __builtin_elementwise_max(sum, zero8);
            if (kk < 4) {
                G1[buf].q = *(const uint4*)(px1 + (kk + 4) * 32);
                G2[buf].q = *(const uint4*)(px2 + (kk + 4) * 32);
            }
            #pragma unroll
            for (int tt = 0; tt < 6; ++tt) {
                f16x8 bf = *(const f16x8*)&w2s[(tt * 16 + l16) * W2_STRIDE + kk * 32 + quad * 8];
                acc[tt] = __builtin_amdgcn_mfma_f32_16x16x32_f16(af, bf, acc[tt], 0, 0, 0);
            }
        }

        const int pairBase = lb * 512 + g * 64 + waveId * 8;

        // issue NEXT group's chunks now; latency hides under dump+payoff
        if (g < 7) {
            computePx(g + 1, px1, px2);
            #pragma unroll
            for (int c = 0; c < 4; ++c) {
                G1[c].q = *(const uint4*)(px1 + c * 32);
                G2[c].q = *(const uint4*)(px2 + c * 32);
            }
        }

        // dump p (+b2, x psc) as f16 into own region [side][pp][i*8+k8]
        #pragma unroll
        for (int tt = 0; tt < 6; ++tt) {
            #pragma unroll
            for (int r = 0; r < 4; ++r)
                pm[d6[tt] + r * PP_STRIDE] = (_Float16)((acc[tt][r] + b2v[tt]) * psc[tt]);
        }

        // payoff: one MFMA per pair, A = V (j rows), B = U (i rows)
        // -> D[col=l16=i][row=quad*4+r=j] -> coalesced float4 stores
        #pragma unroll
        for (int pp = 0; pp < 8; ++pp) {
            f16x8 afp = zero8, bfp = zero8;
            if (quad == 0) {
                afp = *(const f16x8*)&pm[V_OFF + pp * PP_STRIDE + l16 * 8];
                bfp = *(const f16x8*)&pm[pp * PP_STRIDE + l16 * 8];
            }
            f32x4 d = __builtin_amdgcn_mfma_f32_16x16x32_f16(
                afp, bfp, (f32x4){0.f, 0.f, 0.f, 0.f}, 0, 0, 0);
            if (l16 < 12 && quad < 3) {
                float* ob = out + (pairBase + pp) * 144 + l16 * 12 + quad * 4;
                *(float4*)ob = make_float4(d[0], d[1], d[2], d[3]);
            }
        }
    }
}

extern "C" void kernel_launch(void* const* d_in, const int* in_sizes, int n_in,
                              void* d_out, int out_size, void* d_ws, size_t ws_size,
                              hipStream_t stream) {
    const float* hidden = (const float*)d_in[0];
    const float* W1 = (const float*)d_in[1];
    const float* b1 = (const float*)d_in[2];
    const float* W2 = (const float*)d_in[3];
    const float* b2 = (const float*)d_in[4];
    const int* e_f = (const int*)d_in[5];
    const int* e_t = (const int*)d_in[6];
    float* out = (float*)d_out;

    char* ws = (char*)d_ws;
    f16* X = (f16*)ws;                              // X1 then X2, 4 MB each
    f16* w2h = (f16*)(ws + 8 * 1024 * 1024);        // W2 f16 image [96][264] + stage slop

    x_kernel<<<257, 256, 0, stream>>>(hidden, W1, b1, X, W2, w2h);
    gemm_payoff_kernel<<<248, 512, 0, stream>>>(X, X + 8192 * 256, e_f, e_t, w2h, b2, out);
}